// Round 7
// baseline (190.974 us; speedup 1.0000x reference)
//
#include <hip/hip_runtime.h>

// MultiHeadAttention: B=2, N=2048, C=768, H=12, DH=64. fp32 in/out, bf16 MFMA compute.
// R7 = R6 with the staging-coverage bug fixed: each 8192-elem LDS tile needs 16
// chunks of (64 lanes x 8 elems); with 4 waves that is p=0..3, not p=0..1.
// R6 staged only half the tile -> uninitialized LDS -> NaN.

typedef __bf16 bf16_t;
typedef __bf16 bf16x8 __attribute__((ext_vector_type(8)));
typedef __bf16 bf16x4 __attribute__((ext_vector_type(4)));
typedef short  short4_t __attribute__((ext_vector_type(4)));
typedef float  floatx4 __attribute__((ext_vector_type(4)));
typedef unsigned int u32;

#define MFMA32(a, b, c) __builtin_amdgcn_mfma_f32_16x16x32_bf16(a, b, c, 0, 0, 0)

__device__ __forceinline__ void async16(const bf16_t* g, bf16_t* l) {
  __builtin_amdgcn_global_load_lds(
      (const __attribute__((address_space(1))) u32*)g,
      (__attribute__((address_space(3))) u32*)l, 16, 0, 0);
}

// ---------------------------------------------------------------- converts --
__global__ __launch_bounds__(256) void cvt_x_kernel(const float* __restrict__ x,
                                                    bf16_t* __restrict__ xb) {
  int i = blockIdx.x * 256 + threadIdx.x;
  floatx4 v = ((const floatx4*)x)[i];
  bf16x4 o;
  o[0] = (bf16_t)v[0]; o[1] = (bf16_t)v[1]; o[2] = (bf16_t)v[2]; o[3] = (bf16_t)v[3];
  ((bf16x4*)xb)[i] = o;
}

// W [in=768][out=768] fp32 -> WT [out][in] bf16; blockIdx.z picks which matrix.
__global__ __launch_bounds__(256) void cvt_wt_kernel(
    const float* __restrict__ W0, const float* __restrict__ W1,
    const float* __restrict__ W2, const float* __restrict__ W3,
    bf16_t* __restrict__ T0, bf16_t* __restrict__ T1,
    bf16_t* __restrict__ T2, bf16_t* __restrict__ T3) {
  const int z = blockIdx.z;
  const float* W = (z == 0) ? W0 : (z == 1) ? W1 : (z == 2) ? W2 : W3;
  bf16_t* WT = (z == 0) ? T0 : (z == 1) ? T1 : (z == 2) ? T2 : T3;
  __shared__ bf16_t T[64][65];
  const int c = threadIdx.x & 63, r0 = threadIdx.x >> 6;
#pragma unroll
  for (int p = 0; p < 16; ++p) {
    int r = p * 4 + r0;
    T[r][c] = (bf16_t)W[(blockIdx.y * 64 + r) * 768 + blockIdx.x * 64 + c];
  }
  __syncthreads();
#pragma unroll
  for (int p = 0; p < 16; ++p) {
    int r = p * 4 + r0;
    WT[(blockIdx.x * 64 + r) * 768 + blockIdx.y * 64 + c] = T[c][r];
  }
}

// ------------------------------------------------------------------- GEMMs --
// 128x128 tile, BK=64, LDS pitch 64 (no pad: linear for global_load_lds; the
// resulting ds_read conflicts are the m97-accepted cost).

// Fragment-order layouts (per bh, per 128-key tile kt):
//  K: elem(key,d) -> kt*8192 + ((nk*2+kk)*64 + quad*16 + l15)*8 + j
//     nk=key128>>4, l15=key128&15, kk=d>>5, quad=(d>>3)&3, j=d&7
//  V (sigma-permuted for x32 PV): elem(key,d) ->
//     kt*8192 + ((g*4+nd)*64 + qv*16 + dl15)*8 + jv
//     g=key128>>5, o=key128&31, qv=(o&15)>>2, jv=(o&3)+((o&16)>>2),
//     nd=d>>4, dl15=d&15

// Fused QKV, M = output channels (768), N = tokens (4096).
__global__ __launch_bounds__(256) void gemm_qkv(
    const bf16_t* __restrict__ Xb, const bf16_t* __restrict__ WqT,
    const bf16_t* __restrict__ WkT, const bf16_t* __restrict__ WvT,
    const float* __restrict__ bq, const float* __restrict__ bk,
    const float* __restrict__ bv, bf16_t* __restrict__ qw,
    bf16_t* __restrict__ kw, bf16_t* __restrict__ vtw) {
  __shared__ bf16_t Al[128 * 64];
  __shared__ bf16_t Bl[128 * 64];
  const int z = blockIdx.z;
  const bf16_t* Wt = (z == 0) ? WqT : (z == 1) ? WkT : WvT;
  const float* bias = (z == 0) ? bq : (z == 1) ? bk : bv;
  const float oscale = (z == 0) ? 0.18033688011112042f : 1.0f;  // 0.125*log2(e)

  const int tid = threadIdx.x, lane = tid & 63, w = tid >> 6;
  const int wr = w >> 1, wc = w & 1;
  const int l15 = lane & 15, quad = lane >> 4;
  const int m0 = blockIdx.y * 128, n0 = blockIdx.x * 128;

  floatx4 acc[4][4] = {};

  for (int kt = 0; kt < 768; kt += 64) {
#pragma unroll
    for (int p = 0; p < 4; ++p) {               // 16 chunks of 512 elems total
      const int cb = (p * 4 + w) * 64;          // wave-uniform chunk base
      const int c = cb + lane;
      async16(&Wt[(m0 + (c >> 3)) * 768 + kt + (c & 7) * 8], &Al[cb * 8]);
      async16(&Xb[(n0 + (c >> 3)) * 768 + kt + (c & 7) * 8], &Bl[cb * 8]);
    }
    __syncthreads();
#pragma unroll
    for (int kk = 0; kk < 2; ++kk) {
      bf16x8 af[4], bfr[4];
#pragma unroll
      for (int i = 0; i < 4; ++i) {
        af[i]  = *(bf16x8*)&Al[(wr * 64 + i * 16 + l15) * 64 + kk * 32 + quad * 8];
        bfr[i] = *(bf16x8*)&Bl[(wc * 64 + i * 16 + l15) * 64 + kk * 32 + quad * 8];
      }
#pragma unroll
      for (int mi = 0; mi < 4; ++mi)
#pragma unroll
        for (int ni = 0; ni < 4; ++ni)
          acc[mi][ni] = MFMA32(af[mi], bfr[ni], acc[mi][ni]);
    }
    __syncthreads();
  }

  const int hh = (m0 + wr * 64) >> 6;  // head (64-aligned per wave-row)
#pragma unroll
  for (int mi = 0; mi < 4; ++mi) {
    const int d0 = mi * 16 + quad * 4;           // d within head, multiple of 4
    const int gm0 = m0 + wr * 64 + d0;
    float bv4[4];
#pragma unroll
    for (int r = 0; r < 4; ++r) bv4[r] = bias[gm0 + r];
#pragma unroll
    for (int ni = 0; ni < 4; ++ni) {
      const int gn = n0 + wc * 64 + ni * 16 + l15;
      const int bb = gn >> 11, tok = gn & 2047;
      const int bh = bb * 12 + hh;
      if (z == 0) {
        bf16x4 pk;
#pragma unroll
        for (int r = 0; r < 4; ++r)
          pk[r] = (bf16_t)((acc[mi][ni][r] + bv4[r]) * oscale);
        *(bf16x4*)&qw[bh * 131072 + tok * 64 + d0] = pk;
      } else if (z == 1) {
        const int kt2 = tok >> 7, k128 = tok & 127;
        const int nk = k128 >> 4, kl15 = k128 & 15;
        const int kk = d0 >> 5, kq = (d0 >> 3) & 3, j0 = d0 & 7;
        bf16x4 pk;
#pragma unroll
        for (int r = 0; r < 4; ++r)
          pk[r] = (bf16_t)(acc[mi][ni][r] + bv4[r]);
        *(bf16x4*)&kw[bh * 131072 + kt2 * 8192 +
                      ((nk * 2 + kk) * 64 + kq * 16 + kl15) * 8 + j0] = pk;
      } else {
        const int kt2 = tok >> 7, k128 = tok & 127;
        const int g = k128 >> 5, o = k128 & 31;
        const int qv = (o & 15) >> 2, jv = (o & 3) + ((o & 16) >> 2);
        // d = d0 + r -> nd = mi, dl15 = quad*4 + r
        const int base = bh * 131072 + kt2 * 8192 +
                         ((g * 4 + mi) * 64 + qv * 16 + quad * 4) * 8 + jv;
#pragma unroll
        for (int r = 0; r < 4; ++r)
          vtw[base + r * 8] = (bf16_t)(acc[mi][ni][r] + bv4[r]);
      }
    }
  }
}

// Output projection, M = channels: out fp32 [4096 tok][768 ch] via float4 stores.
__global__ __launch_bounds__(256) void gemm_proj(
    const bf16_t* __restrict__ Yb, const bf16_t* __restrict__ WpT,
    const float* __restrict__ bias, float* __restrict__ out) {
  __shared__ bf16_t Al[128 * 64];
  __shared__ bf16_t Bl[128 * 64];
  const int tid = threadIdx.x, lane = tid & 63, w = tid >> 6;
  const int wr = w >> 1, wc = w & 1;
  const int l15 = lane & 15, quad = lane >> 4;
  const int m0 = blockIdx.y * 128, n0 = blockIdx.x * 128;

  floatx4 acc[4][4] = {};

  for (int kt = 0; kt < 768; kt += 64) {
#pragma unroll
    for (int p = 0; p < 4; ++p) {
      const int cb = (p * 4 + w) * 64;
      const int c = cb + lane;
      async16(&WpT[(m0 + (c >> 3)) * 768 + kt + (c & 7) * 8], &Al[cb * 8]);
      async16(&Yb[(n0 + (c >> 3)) * 768 + kt + (c & 7) * 8], &Bl[cb * 8]);
    }
    __syncthreads();
#pragma unroll
    for (int kk = 0; kk < 2; ++kk) {
      bf16x8 af[4], bfr[4];
#pragma unroll
      for (int i = 0; i < 4; ++i) {
        af[i]  = *(bf16x8*)&Al[(wr * 64 + i * 16 + l15) * 64 + kk * 32 + quad * 8];
        bfr[i] = *(bf16x8*)&Bl[(wc * 64 + i * 16 + l15) * 64 + kk * 32 + quad * 8];
      }
#pragma unroll
      for (int mi = 0; mi < 4; ++mi)
#pragma unroll
        for (int ni = 0; ni < 4; ++ni)
          acc[mi][ni] = MFMA32(af[mi], bfr[ni], acc[mi][ni]);
    }
    __syncthreads();
  }

#pragma unroll
  for (int mi = 0; mi < 4; ++mi) {
    const int gm0 = m0 + wr * 64 + mi * 16 + quad * 4;
    floatx4 bv4;
#pragma unroll
    for (int r = 0; r < 4; ++r) bv4[r] = bias[gm0 + r];
#pragma unroll
    for (int ni = 0; ni < 4; ++ni) {
      const int gn = n0 + wc * 64 + ni * 16 + l15;
      floatx4 v = acc[mi][ni] + bv4;
      *(floatx4*)&out[gn * 768 + gm0] = v;
    }
  }
}

// --------------------------------------------------------------- attention --
// Block: one (b,h), 64 Q rows.  Wave w=(wk<<1)|wq: wq = 32-q half, wk = 64-key
// half.  K/V arrive in fragment order -> async linear staging; all frag reads
// lane-contiguous.  PV uses x32 MFMA: pk pairs concat into A-frags, V layout
// pre-permuted by sigma.  End: 2-way cross-wave O reduction via reused LDS.
__global__ __launch_bounds__(256, 4) void attn_kernel(
    const bf16_t* __restrict__ Q, const bf16_t* __restrict__ Kf,
    const bf16_t* __restrict__ Vf, bf16_t* __restrict__ Y) {
  __shared__ __align__(16) bf16_t smem[16384];  // K [0,8192), V [8192,16384)
  __shared__ float Ls[2][2][2][16];             // [wq][wk][ni][q&15]
  bf16_t* Kl = smem;
  bf16_t* Vl = smem + 8192;
  float* Ox = (float*)smem;                     // end-phase exchange (16 KB)

  const int tid = threadIdx.x, lane = tid & 63, w = tid >> 6;
  const int wq = w & 1, wk = w >> 1;
  const int l15 = lane & 15, quad = lane >> 4;
  const int bh = blockIdx.y;
  const int q0 = blockIdx.x * 64;
  const bf16_t* Qb = Q + bh * 131072;
  const bf16_t* Kb = Kf + bh * 131072;
  const bf16_t* Vb = Vf + bh * 131072;

  bf16x8 qf[2][2];
#pragma unroll
  for (int ni = 0; ni < 2; ++ni)
#pragma unroll
    for (int kk = 0; kk < 2; ++kk)
      qf[ni][kk] = *(const bf16x8*)&Qb[(q0 + wq * 32 + ni * 16 + l15) * 64 +
                                       kk * 32 + quad * 8];

  floatx4 oacc[2][4] = {};   // [ni(q16)][nd(d16)] partial over this wave's keys
  float lsum[2] = {0.f, 0.f};

  for (int kt = 0; kt < 16; ++kt) {
    const bf16_t* kg = Kb + kt * 8192;
    const bf16_t* vg = Vb + kt * 8192;
#pragma unroll
    for (int p = 0; p < 4; ++p) {               // 16 chunks per 8192-elem tile
      const int cb = (p * 4 + w) * 64;          // wave-uniform chunk base
      async16(&kg[(cb + lane) * 8], &Kl[cb * 8]);
      async16(&vg[(cb + lane) * 8], &Vl[cb * 8]);
    }
    __syncthreads();

    // S^T = K*Q^T (64 keys x 32 q); P = exp2 packed into x32 A-frags.
    bf16x8 pk32[2][2];  // [g(32key)][ni]
#pragma unroll
    for (int mt = 0; mt < 4; ++mt) {
      floatx4 s[2] = {};
#pragma unroll
      for (int kk = 0; kk < 2; ++kk) {
        bf16x8 kfr = *(bf16x8*)&Kl[((wk * 4 + mt) * 2 + kk) * 512 + lane * 8];
#pragma unroll
        for (int ni = 0; ni < 2; ++ni)
          s[ni] = MFMA32(kfr, qf[ni][kk], s[ni]);
      }
#pragma unroll
      for (int ni = 0; ni < 2; ++ni)
#pragma unroll
        for (int r = 0; r < 4; ++r) {
          const float pv = __builtin_amdgcn_exp2f(s[ni][r]);
          lsum[ni] += pv;
          pk32[mt >> 1][ni][(mt & 1) * 4 + r] = (bf16_t)pv;
        }
    }

    // O += P*V (x32): V B-frag b128 lane-contiguous, sigma-permuted keys.
#pragma unroll
    for (int g = 0; g < 2; ++g)
#pragma unroll
      for (int nd = 0; nd < 4; ++nd) {
        bf16x8 vfr = *(bf16x8*)&Vl[(((wk * 2 + g) * 4 + nd) * 64 + lane) * 8];
#pragma unroll
        for (int ni = 0; ni < 2; ++ni)
          oacc[ni][nd] = MFMA32(pk32[g][ni], vfr, oacc[ni][nd]);
      }
    __syncthreads();
  }

  // lsum: reduce across quads -> wave total for q = ni*16 + l15.
#pragma unroll
  for (int ni = 0; ni < 2; ++ni) {
    lsum[ni] += __shfl_xor(lsum[ni], 16);
    lsum[ni] += __shfl_xor(lsum[ni], 32);
  }
  if (quad == 0) {
#pragma unroll
    for (int ni = 0; ni < 2; ++ni) Ls[wq][wk][ni][l15] = lsum[ni];
  }

  // Each wave writes its NON-owned d-half, reads partner's for its owned half.
#pragma unroll
  for (int ni = 0; ni < 2; ++ni)
#pragma unroll
    for (int ndl = 0; ndl < 2; ++ndl) {
      const int nd = (1 - wk) * 2 + ndl;
      *(floatx4*)&Ox[((((wq * 2 + wk) * 2 + ni) * 2 + ndl) * 64 + lane) * 4] =
          oacc[ni][nd];
    }
  __syncthreads();

  const int bb = bh / 12, h = bh % 12;
#pragma unroll
  for (int ni = 0; ni < 2; ++ni) {
    float tot[4];
#pragma unroll
    for (int r = 0; r < 4; ++r)
      tot[r] = Ls[wq][0][ni][quad * 4 + r] + Ls[wq][1][ni][quad * 4 + r];
#pragma unroll
    for (int ndl = 0; ndl < 2; ++ndl) {
      const int nd = wk * 2 + ndl;
      floatx4 o = oacc[ni][nd];
      floatx4 other =
          *(floatx4*)&Ox[((((wq * 2 + (1 - wk)) * 2 + ni) * 2 + ndl) * 64 + lane) * 4];
      o += other;
#pragma unroll
      for (int r = 0; r < 4; ++r) {
        const int tok = q0 + wq * 32 + ni * 16 + quad * 4 + r;
        const int col = h * 64 + nd * 16 + l15;
        Y[(bb * 2048 + tok) * 768 + col] = (bf16_t)(o[r] / tot[r]);
      }
    }
  }
}

// ------------------------------------------------------------------ launch --
extern "C" void kernel_launch(void* const* d_in, const int* in_sizes, int n_in,
                              void* d_out, int out_size, void* d_ws, size_t ws_size,
                              hipStream_t stream) {
  const float* x  = (const float*)d_in[0];
  const float* Wq = (const float*)d_in[1];
  const float* bq = (const float*)d_in[2];
  const float* Wk = (const float*)d_in[3];
  const float* bk = (const float*)d_in[4];
  const float* Wv = (const float*)d_in[5];
  const float* bv = (const float*)d_in[6];
  const float* Wp = (const float*)d_in[7];
  const float* bp = (const float*)d_in[8];
  float* out = (float*)d_out;

  char* ws = (char*)d_ws;
  bf16_t* xb  = (bf16_t*)ws; ws += (size_t)4096 * 768 * 2;
  bf16_t* WqT = (bf16_t*)ws; ws += (size_t)768 * 768 * 2;
  bf16_t* WkT = (bf16_t*)ws; ws += (size_t)768 * 768 * 2;
  bf16_t* WvT = (bf16_t*)ws; ws += (size_t)768 * 768 * 2;
  bf16_t* WpT = (bf16_t*)ws; ws += (size_t)768 * 768 * 2;
  bf16_t* qw  = (bf16_t*)ws; ws += (size_t)24 * 2048 * 64 * 2;
  bf16_t* kw  = (bf16_t*)ws; ws += (size_t)24 * 2048 * 64 * 2;
  bf16_t* vtw = (bf16_t*)ws; ws += (size_t)24 * 2048 * 64 * 2;
  bf16_t* yw  = (bf16_t*)ws; ws += (size_t)4096 * 768 * 2;

  cvt_x_kernel<<<3072, 256, 0, stream>>>(x, xb);
  cvt_wt_kernel<<<dim3(12, 12, 4), 256, 0, stream>>>(Wq, Wk, Wv, Wp, WqT, WkT, WvT, WpT);

  gemm_qkv<<<dim3(32, 6, 3), 256, 0, stream>>>(xb, WqT, WkT, WvT, bq, bk, bv, qw, kw, vtw);
  attn_kernel<<<dim3(32, 24), 256, 0, stream>>>(qw, kw, vtw, yw);
  gemm_proj<<<dim3(32, 6), 256, 0, stream>>>(yw, WpT, bp, out);
}